// Round 17
// baseline (993.809 us; speedup 1.0000x reference)
//
#include <hip/hip_runtime.h>

#define NN 100000
#define EE 1700000
#define F1 256
#define NH 8
#define HF 64
#define C1 512
#define C2 40
#define EPS 1e-6f

// ---- ws layout (bytes) ----
#define OF_PF1   ((size_t)0)                       // N*512*2 bf16 (ft1 -> pf1 in place)
#define OF_HCAT  (OF_PF1  + 102400000ULL)          // N*512*2 f16 hcat; pre-agg1 reused as xh/Wh; post-gemm2 reused as pf2h
#define OF_FT2   (OF_HCAT + 102400000ULL)          // N*40*4 f32
#define OF_EL1   (OF_FT2  + 16000000ULL)           // N*8*4
#define OF_ER1   (OF_EL1  + 3200000ULL)
#define OF_EL2   (OF_ER1  + 3200000ULL)            // N*4
#define OF_ER2   (OF_EL2  + 400000ULL)
#define OF_DEG   (OF_ER2  + 400000ULL)             // N*4
#define OF_OFFS  (OF_DEG  + 400000ULL)             // (N+1)*4 padded
#define OF_CUR   (OF_OFFS + 400128ULL)             // N*4
#define OF_SRCC  (OF_CUR  + 400000ULL)             // E*4
#define OF_BSUM  (OF_SRCC + 6800000ULL)            // 2048
#define OF_BOFF  (OF_BSUM + 2048ULL)               // 2048
#define OF_PRM   (OF_BOFF + 2048ULL)               // params block (1KB)
#define OF_W2H   (OF_PRM  + 1024ULL)               // 48*512*2 = 49KB f16
// overlays inside HCAT region:
#define OF_XH    (OF_HCAT)                         // x f16, 51.2MB (dead after gemm1)
#define OF_WH    (OF_HCAT + 51200000ULL)           // W1 f16, 256KB (dead after gemm1)
#define OF_PF2H  (OF_HCAT)                         // pf2 f16, 8MB (written after gemm2; hcat dead)

// params block: [0..7] minkey1(u32), [8] minkey2(u32), [16..23] pe1, [24..31] ipe1, [32] pe2, [33] ipe2

typedef _Float16 f16x8 __attribute__((ext_vector_type(8)));
typedef _Float16 f16x4 __attribute__((ext_vector_type(4)));
typedef float f32x4 __attribute__((ext_vector_type(4)));

__device__ __forceinline__ unsigned f2key(float f){
  unsigned u = __float_as_uint(f);
  return (u & 0x80000000u) ? ~u : (u | 0x80000000u);
}
__device__ __forceinline__ float key2f(unsigned k){
  unsigned u = (k & 0x80000000u) ? (k & 0x7FFFFFFFu) : ~k;
  return __uint_as_float(u);
}
__device__ __forceinline__ unsigned short f2b(float f){  // f32 -> bf16 RNE
  unsigned u = __float_as_uint(f);
  unsigned r = u + 0x7FFFu + ((u >> 16) & 1u);
  return (unsigned short)(r >> 16);
}
__device__ __forceinline__ float b2f(unsigned short b){
  return __uint_as_float(((unsigned)b) << 16);
}
__device__ __forceinline__ float leaky(float e){ return e >= 0.f ? e : 0.2f*e; }

__device__ __forceinline__ void gload16(const _Float16* g, char* l){
  __builtin_amdgcn_global_load_lds((const __attribute__((address_space(1))) void*)g,
                                   (__attribute__((address_space(3))) void*)l, 16, 0, 0);
}

// ---------------- init ----------------
__global__ void k_init(const float* __restrict__ p1, const float* __restrict__ p2, unsigned* __restrict__ prm){
  int t = threadIdx.x;
  float* prf = (float*)prm;
  if (t < 8){
    prm[t] = 0xFFFFFFFFu;
    float pe = 1.f/(1.f + __expf(-p1[t])) + 1.0f;
    prf[16 + t] = pe;
    prf[24 + t] = 1.f/pe;
  }
  if (t == 0){
    prm[8] = 0xFFFFFFFFu;
    float pe = 1.f/(1.f + __expf(-p2[0])) + 1.0f;
    prf[32] = pe;
    prf[33] = 1.f/pe;
  }
}

__global__ void k_zero_deg(int* __restrict__ deg){
  int i = blockIdx.x*256 + threadIdx.x;
  if (i < NN) deg[i] = 0;
}

// ---------------- f32 -> f16 convert (8 elems/thread); used for x and W1 ----------------
__global__ void k_cvt16(const float* __restrict__ in, _Float16* __restrict__ out){
  int i = blockIdx.x*256 + threadIdx.x;
  const float4* p = (const float4*)in + (size_t)i*2;
  float4 a = p[0], b = p[1];
  f16x8 h = {(_Float16)a.x,(_Float16)a.y,(_Float16)a.z,(_Float16)a.w,
             (_Float16)b.x,(_Float16)b.y,(_Float16)b.z,(_Float16)b.w};
  *((f16x8*)out + i) = h;
}

// W2 [40][512] f32 -> W2h [48][512] f16, rows 40..47 zero
__global__ void k_cvtW2(const float* __restrict__ W2, _Float16* __restrict__ W2h){
  int i = blockIdx.x*256 + threadIdx.x;   // 96 blocks: 24576 elems
  int row = i >> 9, col = i & 511;
  W2h[i] = (row < C2) ? (_Float16)W2[row*C1 + col] : (_Float16)0.f;
}

// ---------------- GEMM1 (MFMA fp16, single-barrier, 64x128 tile) + fused el1/er1 + per-head min ----------------
// r16 post-mortem: single-barrier fixed the drains but 64KB LDS -> 2 blocks/CU; a 2.7us A-stage
// can't hide behind ~1us of neighbor compute. BM=64: A=32KB once -> ~5 blocks/CU resident,
// stage 1.35us each, 4 neighbors overlap. kg order unchanged -> bit-identical output.
#define G1_BM 64
#define G1_BN 128
__global__ __launch_bounds__(256) void k_gemm1(const _Float16* __restrict__ xh, const _Float16* __restrict__ Wh,
                                               const float* __restrict__ al1, const float* __restrict__ ar1,
                                               unsigned short* __restrict__ ft1b,
                                               float* __restrict__ el1, float* __restrict__ er1,
                                               unsigned* __restrict__ prm){
  __shared__ __align__(16) char smem[32768];     // A: 64 rows x 32 granules(16B)
  char* Abase = smem;
  unsigned short (*Cs)[136] = (unsigned short (*)[136])smem;  // 64x136x2 = 17408B overlay

  int t = threadIdx.x;
  int lane = t & 63, w = t >> 6;
  int wr = w >> 1, wc = w & 1;     // wave = 32 rows x 64 cols (one head)
  int ct = blockIdx.x * G1_BN;
  int rt = blockIdx.y * G1_BM;

  // stage A full-K: 2048 granules, 8/thread; slot (row,gs) holds logical g = (gs&7)^(row&7) | (gs&24)
  #pragma unroll
  for (int p = 0; p < 8; p++){
    int idx = p*256 + t;                 // wave-uniform base + lane
    int row = idx >> 5, gs = idx & 31;
    int glog = ((gs & 7) ^ (row & 7)) | (gs & 24);
    int ga = min(rt + row, NN-1);
    gload16(xh + (size_t)ga*F1 + glog*8, Abase + idx*16);
  }
  __syncthreads();   // the ONLY staging barrier

  f32x4 zero = {0.f,0.f,0.f,0.f};
  f32x4 acc[2][4];
  #pragma unroll
  for (int m=0;m<2;m++)
    #pragma unroll
    for (int n=0;n<4;n++) acc[m][n] = zero;

  int arow0 = wr*32 + (lane & 15);
  int brow0 = ct + wc*64 + (lane & 15);
  int ksub  = (lane >> 4)*8;

  #pragma unroll
  for (int kg = 0; kg < 8; kg++){
    int g = kg*4 + (lane >> 4);
    f16x8 af[2], bf[4];
    #pragma unroll
    for (int m=0;m<2;m++){
      int row = arow0 + m*16;
      int gslot = ((g & 7) ^ (row & 7)) | (g & 24);
      af[m] = *(f16x8*)(Abase + ((row*32 + gslot)<<4));
    }
    #pragma unroll
    for (int n=0;n<4;n++){
      bf[n] = *(const f16x8*)(Wh + (size_t)(brow0 + n*16)*F1 + kg*32 + ksub);
    }
    #pragma unroll
    for (int m=0;m<2;m++)
      #pragma unroll
      for (int n=0;n<4;n++)
        acc[m][n] = __builtin_amdgcn_mfma_f32_16x16x32_f16(af[m], bf[n], acc[m][n], 0, 0, 0);
  }
  __syncthreads();   // A dead; Cs overlay becomes safe

  // epilogue: bf16 tile -> LDS; per-head min; fused el1/er1 (wave owns (32-row block, head))
  int h = (ct >> 6) + wc;
  int c0 = lane & 15;
  float alc[4], arc[4];
  #pragma unroll
  for (int n=0;n<4;n++){
    alc[n] = al1[h*HF + n*16 + c0];
    arc[n] = ar1[h*HF + n*16 + c0];
  }
  unsigned kmin = 0xFFFFFFFFu;
  #pragma unroll
  for (int m=0;m<2;m++){
    float elp[4] = {0.f,0.f,0.f,0.f};
    float erp[4] = {0.f,0.f,0.f,0.f};
    #pragma unroll
    for (int n=0;n<4;n++){
      int cl = wc*64 + n*16 + c0;
      int rl = wr*32 + m*16 + (lane >> 4)*4;
      #pragma unroll
      for (int j=0;j<4;j++){
        unsigned short ub = f2b(acc[m][n][j]);
        float vr = b2f(ub);
        Cs[rl + j][cl] = ub;
        kmin = min(kmin, f2key(vr));
        elp[j] += vr*alc[n];
        erp[j] += vr*arc[n];
      }
    }
    #pragma unroll
    for (int j=0;j<4;j++){
      #pragma unroll
      for (int off=1; off<16; off<<=1){
        elp[j] += __shfl_xor(elp[j], off);
        erp[j] += __shfl_xor(erp[j], off);
      }
      int row = rt + wr*32 + m*16 + (lane >> 4)*4 + j;
      if (c0 == 0 && row < NN){
        el1[(size_t)row*8 + h] = elp[j];
        er1[(size_t)row*8 + h] = erp[j];
      }
    }
  }
  #pragma unroll
  for (int off=1; off<64; off<<=1) kmin = min(kmin, (unsigned)__shfl_xor((int)kmin, off));
  if (lane == 0) atomicMin(&prm[h], kmin);
  __syncthreads();

  // coalesced store: 64 rows x 16 q-chunks = 1024 uint4, 4 passes
  #pragma unroll
  for (int p = 0; p < 4; p++){
    int flat = p*256 + t;
    int row = flat >> 4;
    int q   = flat & 15;
    int gr = rt + row;
    if (gr < NN){
      uint4 v = *(const uint4*)&Cs[row][q*8];
      *(uint4*)&ft1b[(size_t)gr*C1 + ct + q*8] = v;
    }
  }
}

// ---------------- CSR build ----------------
__global__ void k_count(const int* __restrict__ dst, int* __restrict__ deg){
  int e = blockIdx.x*256 + threadIdx.x;
  if (e < EE) atomicAdd(&deg[dst[e]], 1);
}
__global__ void k_scan1(const int* __restrict__ deg, int* __restrict__ offs, int* __restrict__ bsum){
  __shared__ int s[256];
  int t = threadIdx.x; int i = blockIdx.x*256 + t;
  int v = (i < NN) ? deg[i] : 0;
  s[t] = v; __syncthreads();
  for (int off=1; off<256; off<<=1){
    int tmp = (t>=off) ? s[t-off] : 0;
    __syncthreads(); s[t] += tmp; __syncthreads();
  }
  if (i < NN) offs[i] = s[t] - v;
  if (t == 255) bsum[blockIdx.x] = s[255];
}
__global__ void k_scan2(int* __restrict__ bsum, int* __restrict__ boff, int nb){
  __shared__ int s[512];
  int t = threadIdx.x;
  int v = (t < nb) ? bsum[t] : 0;
  s[t] = v; __syncthreads();
  for (int off=1; off<512; off<<=1){
    int tmp = (t>=off) ? s[t-off] : 0;
    __syncthreads(); s[t] += tmp; __syncthreads();
  }
  if (t < nb) boff[t] = s[t] - v;
}
__global__ void k_scan3(int* __restrict__ offs, int* __restrict__ cur, const int* __restrict__ boff){
  int i = blockIdx.x*256 + threadIdx.x;
  if (i < NN){
    int v = offs[i] + boff[blockIdx.x];
    offs[i] = v; cur[i] = v;
  }
  if (i == 0) offs[NN] = EE;
}
__global__ void k_fill(const int* __restrict__ src, const int* __restrict__ dst,
                       int* __restrict__ cur, int* __restrict__ srcc){
  int e = blockIdx.x*256 + threadIdx.x;
  if (e < EE){
    int d = dst[e];
    int pos = atomicAdd(&cur[d], 1);
    srcc[pos] = src[e];
  }
}

// ---------------- pf1: elementwise pow in place (bf16, 8/thread) ----------------
__global__ void k_pf1(unsigned short* __restrict__ ft1b, const unsigned* __restrict__ prm){
  int i = blockIdx.x*256 + threadIdx.x;
  const float* prf = (const float*)prm;
  int h = (i >> 3) & 7;
  float mu = key2f(prm[h]);
  float pe = prf[16 + h];
  uint4 q = ((const uint4*)ft1b)[i];
  unsigned r0, r1, r2, r3;
  float v0, v1;
  v0 = b2f((unsigned short)(q.x & 0xFFFFu)) - mu + EPS;
  v1 = b2f((unsigned short)(q.x >> 16)) - mu + EPS;
  r0 = (unsigned)f2b(__expf(pe*__logf(v0))) | ((unsigned)f2b(__expf(pe*__logf(v1))) << 16);
  v0 = b2f((unsigned short)(q.y & 0xFFFFu)) - mu + EPS;
  v1 = b2f((unsigned short)(q.y >> 16)) - mu + EPS;
  r1 = (unsigned)f2b(__expf(pe*__logf(v0))) | ((unsigned)f2b(__expf(pe*__logf(v1))) << 16);
  v0 = b2f((unsigned short)(q.z & 0xFFFFu)) - mu + EPS;
  v1 = b2f((unsigned short)(q.z >> 16)) - mu + EPS;
  r2 = (unsigned)f2b(__expf(pe*__logf(v0))) | ((unsigned)f2b(__expf(pe*__logf(v1))) << 16);
  v0 = b2f((unsigned short)(q.w & 0xFFFFu)) - mu + EPS;
  v1 = b2f((unsigned short)(q.w >> 16)) - mu + EPS;
  r3 = (unsigned)f2b(__expf(pe*__logf(v0))) | ((unsigned)f2b(__expf(pe*__logf(v1))) << 16);
  ((uint4*)ft1b)[i] = make_uint4(r0, r1, r2, r3);
}

// ---------------- layer-1 fused attention + aggregation + elu (2 edge slots in pass 3) ----------------
__global__ __launch_bounds__(256) void k_agg1(const unsigned short* __restrict__ pf1b,
    const float* __restrict__ el1, const float* __restrict__ er1,
    const int* __restrict__ offs, const int* __restrict__ srcc,
    const float* __restrict__ b1, const unsigned* __restrict__ prm,
    _Float16* __restrict__ hcath){
  int lane = threadIdx.x & 63; int w = threadIdx.x >> 6;
  int v = blockIdx.x*4 + w;
  if (v >= NN) return;
  const float* prf = (const float*)prm;
  int h = lane >> 3;
  int s = lane & 7;
  int start = offs[v], end = offs[v+1];
  float erh = er1[(size_t)v*8 + h];

  float m = -INFINITY;
  for (int pos = start + s; pos < end; pos += 8){
    int u = srcc[pos];
    float e = leaky(el1[(size_t)u*8 + h] + erh);
    m = fmaxf(m, e);
  }
  m = fmaxf(m, __shfl_xor(m,1)); m = fmaxf(m, __shfl_xor(m,2)); m = fmaxf(m, __shfl_xor(m,4));
  float S = 0.f;
  for (int pos = start + s; pos < end; pos += 8){
    int u = srcc[pos];
    float e = leaky(el1[(size_t)u*8 + h] + erh);
    S += __expf(e - m);
  }
  S += __shfl_xor(S,1); S += __shfl_xor(S,2); S += __shfl_xor(S,4);
  float invS = 1.f / S;

  int es = lane >> 5;
  int hc = (lane >> 2) & 7;
  int q4 = lane & 3;
  float mh    = __shfl(m,    hc*8);
  float invSh = __shfl(invS, hc*8);
  float erhc  = __shfl(erh,  hc*8);

  float acc[16];
  #pragma unroll
  for (int j=0;j<16;j++) acc[j]=0.f;
  for (int pos = start + es; pos < end; pos += 2){
    int u = srcc[pos];
    float e = leaky(el1[(size_t)u*8 + hc] + erhc);
    float a = __expf(e - mh) * invSh;
    const unsigned short* pr = &pf1b[(size_t)u*C1 + hc*HF + q4*16];
    uint4 qa = *(const uint4*)pr;
    uint4 qb = *(const uint4*)(pr + 8);
    acc[0]  += a*b2f((unsigned short)(qa.x & 0xFFFFu));
    acc[1]  += a*b2f((unsigned short)(qa.x >> 16));
    acc[2]  += a*b2f((unsigned short)(qa.y & 0xFFFFu));
    acc[3]  += a*b2f((unsigned short)(qa.y >> 16));
    acc[4]  += a*b2f((unsigned short)(qa.z & 0xFFFFu));
    acc[5]  += a*b2f((unsigned short)(qa.z >> 16));
    acc[6]  += a*b2f((unsigned short)(qa.w & 0xFFFFu));
    acc[7]  += a*b2f((unsigned short)(qa.w >> 16));
    acc[8]  += a*b2f((unsigned short)(qb.x & 0xFFFFu));
    acc[9]  += a*b2f((unsigned short)(qb.x >> 16));
    acc[10] += a*b2f((unsigned short)(qb.y & 0xFFFFu));
    acc[11] += a*b2f((unsigned short)(qb.y >> 16));
    acc[12] += a*b2f((unsigned short)(qb.z & 0xFFFFu));
    acc[13] += a*b2f((unsigned short)(qb.z >> 16));
    acc[14] += a*b2f((unsigned short)(qb.w & 0xFFFFu));
    acc[15] += a*b2f((unsigned short)(qb.w >> 16));
  }
  #pragma unroll
  for (int j=0;j<16;j++) acc[j] += __shfl_xor(acc[j], 32);

  float mu = key2f(prm[hc]);
  float ipe = prf[24+hc];
  int fb = q4*16 + es*8;
  f16x8 o;
  #pragma unroll
  for (int j=0;j<8;j++){
    float r = __expf(ipe * __logf(acc[es*8 + j] + EPS)) + mu + b1[hc*HF + fb + j];
    o[j] = (_Float16)((r > 0.f) ? r : (__expf(r) - 1.f));
  }
  *(f16x8*)&hcath[(size_t)v*C1 + hc*HF + fb] = o;
}

// ---------------- GEMM2 (MFMA fp16, 44KB LDS, fused el2/er2/min epilogue) ----------------
__global__ __launch_bounds__(256) void k_gemm2(const _Float16* __restrict__ hcath, const _Float16* __restrict__ W2h,
    float* __restrict__ ft2, float* __restrict__ el2, float* __restrict__ er2,
    const float* __restrict__ al2, const float* __restrict__ ar2, unsigned* __restrict__ prm){
  __shared__ __align__(16) char smem[45056];
  char* Abase = smem;            // 32KB: [128 rows][16 granules]
  char* Bbase = smem + 32768;    // 12KB: [48 rows][16 granules]
  __shared__ unsigned mk;
  int t = threadIdx.x;
  int lane = t & 63, w = t >> 6;
  int rt = blockIdx.x * 128;
  if (t == 0) mk = 0xFFFFFFFFu;

  f32x4 zero = {0.f,0.f,0.f,0.f};
  f32x4 acc[2][3];
  #pragma unroll
  for (int m=0;m<2;m++)
    #pragma unroll
    for (int n=0;n<3;n++) acc[m][n] = zero;

  for (int step = 0; step < 4; step++){
    #pragma unroll
    for (int p = 0; p < 8; p++){
      int idx = p*256 + t;
      int row = idx >> 4, g = idx & 15;
      int ga = min(rt + row, NN-1);
      gload16(hcath + (size_t)ga*C1 + step*128 + ((g ^ (row & 7))<<3), Abase + idx*16);
    }
    #pragma unroll
    for (int p = 0; p < 3; p++){
      int idx = p*256 + t;
      int row = idx >> 4, g = idx & 15;
      gload16(W2h + (size_t)row*C1 + step*128 + ((g ^ (row & 7))<<3), Bbase + idx*16);
    }
    __syncthreads();
    #pragma unroll
    for (int kk = 0; kk < 4; kk++){
      f16x8 af[2], bf[3];
      #pragma unroll
      for (int m=0;m<2;m++){
        int row = w*32 + m*16 + (lane & 15);
        int g = kk*4 + (lane >> 4);
        af[m] = *(f16x8*)(Abase + ((row*16 + (g ^ (row & 7)))<<4));
      }
      #pragma unroll
      for (int n=0;n<3;n++){
        int row = n*16 + (lane & 15);
        int g = kk*4 + (lane >> 4);
        bf[n] = *(f16x8*)(Bbase + ((row*16 + (g ^ (row & 7)))<<4));
      }
      #pragma unroll
      for (int m=0;m<2;m++)
        #pragma unroll
        for (int n=0;n<3;n++)
          acc[m][n] = __builtin_amdgcn_mfma_f32_16x16x32_f16(af[m], bf[n], acc[m][n], 0, 0, 0);
    }
    __syncthreads();
  }

  int c0 = lane & 15;
  unsigned kmin = 0xFFFFFFFFu;
  #pragma unroll
  for (int m=0;m<2;m++){
    float elp[4] = {0.f,0.f,0.f,0.f};
    float erp[4] = {0.f,0.f,0.f,0.f};
    #pragma unroll
    for (int n=0;n<3;n++){
      int col = n*16 + c0;
      bool okc = (col < C2);
      float alc = okc ? al2[col] : 0.f;
      float arc = okc ? ar2[col] : 0.f;
      int rbase = rt + w*32 + m*16 + (lane >> 4)*4;
      #pragma unroll
      for (int j=0;j<4;j++){
        float vv = acc[m][n][j];
        int row = rbase + j;
        if (okc && row < NN){
          ft2[(size_t)row*C2 + col] = vv;
          elp[j] += vv*alc; erp[j] += vv*arc;
          kmin = min(kmin, f2key(vv));
        }
      }
    }
    #pragma unroll
    for (int j=0;j<4;j++){
      #pragma unroll
      for (int off=1; off<16; off<<=1){
        elp[j] += __shfl_xor(elp[j], off);
        erp[j] += __shfl_xor(erp[j], off);
      }
      int row = rt + w*32 + m*16 + (lane >> 4)*4 + j;
      if (c0 == 0 && row < NN){ el2[row] = elp[j]; er2[row] = erp[j]; }
    }
  }
  #pragma unroll
  for (int off=1; off<64; off<<=1) kmin = min(kmin, (unsigned)__shfl_xor((int)kmin, off));
  if (lane == 0) atomicMin(&mk, kmin);
  __syncthreads();
  if (t == 0) atomicMin(&prm[8], mk);
}

// ---------------- transform2: pf2h (f16) = pow(ft2 - mu + eps, pe) ----------------
__global__ void k_transform2(const float* __restrict__ ft2, _Float16* __restrict__ pf2h,
                             const unsigned* __restrict__ prm){
  int i = blockIdx.x*256 + threadIdx.x;
  if (i >= NN*C2) return;
  const float* prf = (const float*)prm;
  float mu = key2f(prm[8]);
  float pe = prf[32];
  float v = ft2[i];
  pf2h[i] = (_Float16)__expf(pe * __logf(v - mu + EPS));
}

// ---------------- layer-2 fused attention + aggregation + log_softmax (online softmax + edge-parallel) ----------------
__global__ __launch_bounds__(256) void k_agg2(const _Float16* __restrict__ pf2h,
    const float* __restrict__ el2, const float* __restrict__ er2,
    const int* __restrict__ offs, const int* __restrict__ srcc,
    const float* __restrict__ b2, const unsigned* __restrict__ prm,
    float* __restrict__ out){
  int lane = threadIdx.x & 63; int w = threadIdx.x >> 6;
  int v = blockIdx.x*4 + w;
  if (v >= NN) return;
  const float* prf = (const float*)prm;
  int start = offs[v], end = offs[v+1];
  float erv = er2[v];

  float m = -INFINITY, S = 0.f;
  for (int pos = start + lane; pos < end; pos += 64){
    float e = leaky(el2[srcc[pos]] + erv);
    float d = e - m;
    if (d > 0.f){ S = S*__expf(-d) + 1.f; m = e; }
    else S += __expf(d);
  }
  float mAll = m;
  #pragma unroll
  for (int off=1; off<64; off<<=1) mAll = fmaxf(mAll, __shfl_xor(mAll, off));
  S *= __expf(m - mAll);
  #pragma unroll
  for (int off=1; off<64; off<<=1) S += __shfl_xor(S, off);
  float invS = 1.f / S;
  m = mAll;

  int s = lane >> 4;
  int c = lane & 15;
  float a0=0.f, a1=0.f, a2=0.f, a3=0.f;
  for (int pos = start + s; pos < end; pos += 4){
    int u = srcc[pos];
    float a = __expf(leaky(el2[u] + erv) - m) * invS;
    if (c < 10){
      f16x4 q = *(const f16x4*)&pf2h[(size_t)u*C2 + c*4];
      a0 += a*(float)q[0]; a1 += a*(float)q[1]; a2 += a*(float)q[2]; a3 += a*(float)q[3];
    }
  }
  a0 += __shfl_xor(a0,16); a1 += __shfl_xor(a1,16); a2 += __shfl_xor(a2,16); a3 += __shfl_xor(a3,16);
  a0 += __shfl_xor(a0,32); a1 += __shfl_xor(a1,32); a2 += __shfl_xor(a2,32); a3 += __shfl_xor(a3,32);

  float y[4];
  float mx;
  if (c < 10){
    float mu = key2f(prm[8]);
    float ipe = prf[33];
    float av[4] = {a0,a1,a2,a3};
    #pragma unroll
    for (int j=0;j<4;j++) y[j] = __expf(ipe * __logf(av[j] + EPS)) + mu + b2[c*4 + j];
    mx = fmaxf(fmaxf(y[0],y[1]), fmaxf(y[2],y[3]));
  } else {
    y[0]=y[1]=y[2]=y[3]=-INFINITY;
    mx = -INFINITY;
  }
  mx = fmaxf(mx, __shfl_xor(mx,1)); mx = fmaxf(mx, __shfl_xor(mx,2));
  mx = fmaxf(mx, __shfl_xor(mx,4)); mx = fmaxf(mx, __shfl_xor(mx,8));
  float se = 0.f;
  if (c < 10){
    #pragma unroll
    for (int j=0;j<4;j++) se += __expf(y[j] - mx);
  }
  se += __shfl_xor(se,1); se += __shfl_xor(se,2); se += __shfl_xor(se,4); se += __shfl_xor(se,8);
  float ls = __logf(se);
  if (s == 0 && c < 10){
    float4 o = make_float4(y[0]-mx-ls, y[1]-mx-ls, y[2]-mx-ls, y[3]-mx-ls);
    *(float4*)&out[(size_t)v*C2 + c*4] = o;
  }
}

// ---------------- host ----------------
extern "C" void kernel_launch(void* const* d_in, const int* in_sizes, int n_in,
                              void* d_out, int out_size, void* d_ws, size_t ws_size,
                              hipStream_t stream){
  const float* x   = (const float*)d_in[0];
  const int*   src = (const int*)d_in[1];
  const int*   dst = (const int*)d_in[2];
  const float* W1  = (const float*)d_in[3];
  const float* al1 = (const float*)d_in[4];
  const float* ar1 = (const float*)d_in[5];
  const float* b1  = (const float*)d_in[6];
  const float* p1  = (const float*)d_in[7];
  const float* W2  = (const float*)d_in[8];
  const float* al2 = (const float*)d_in[9];
  const float* ar2 = (const float*)d_in[10];
  const float* b2  = (const float*)d_in[11];
  const float* p2  = (const float*)d_in[12];
  float* out = (float*)d_out;
  char* ws = (char*)d_ws;

  unsigned short* pf1b  = (unsigned short*)(ws + OF_PF1);
  _Float16* hcath = (_Float16*)(ws + OF_HCAT);
  _Float16* xh  = (_Float16*)(ws + OF_XH);
  _Float16* Wh  = (_Float16*)(ws + OF_WH);
  _Float16* W2h = (_Float16*)(ws + OF_W2H);
  _Float16* pf2h = (_Float16*)(ws + OF_PF2H);
  float* ft2   = (float*)(ws + OF_FT2);
  float* el1   = (float*)(ws + OF_EL1);
  float* er1   = (float*)(ws + OF_ER1);
  float* el2   = (float*)(ws + OF_EL2);
  float* er2   = (float*)(ws + OF_ER2);
  int*   deg   = (int*)(ws + OF_DEG);
  int*   offs  = (int*)(ws + OF_OFFS);
  int*   cur   = (int*)(ws + OF_CUR);
  int*   srcc  = (int*)(ws + OF_SRCC);
  int*   bsum  = (int*)(ws + OF_BSUM);
  int*   boff  = (int*)(ws + OF_BOFF);
  unsigned* prm = (unsigned*)(ws + OF_PRM);

  const int NB1 = (NN + 255)/256;
  const int NBE = (EE + 255)/256;

  k_init<<<1, 64, 0, stream>>>(p1, p2, prm);
  k_zero_deg<<<NB1, 256, 0, stream>>>(deg);
  k_cvt16<<<12500, 256, 0, stream>>>(x, xh);
  k_cvt16<<<64, 256, 0, stream>>>(W1, Wh);
  k_cvtW2<<<96, 256, 0, stream>>>(W2, W2h);
  k_gemm1<<<dim3(C1/G1_BN, (NN + G1_BM - 1)/G1_BM), 256, 0, stream>>>(xh, Wh, al1, ar1, pf1b, el1, er1, prm);
  k_count<<<NBE, 256, 0, stream>>>(dst, deg);
  k_scan1<<<NB1, 256, 0, stream>>>(deg, offs, bsum);
  k_scan2<<<1, 512, 0, stream>>>(bsum, boff, NB1);
  k_scan3<<<NB1, 256, 0, stream>>>(offs, cur, boff);
  k_fill<<<NBE, 256, 0, stream>>>(src, dst, cur, srcc);
  k_pf1<<<25000, 256, 0, stream>>>(pf1b, prm);
  k_agg1<<<NN/4, 256, 0, stream>>>(pf1b, el1, er1, offs, srcc, b1, prm, hcath);
  k_gemm2<<<(NN + 127)/128, 256, 0, stream>>>(hcath, W2h, ft2, el2, er2, al2, ar2, prm);
  k_transform2<<<(NN*C2 + 255)/256, 256, 0, stream>>>(ft2, pf2h, prm);
  k_agg2<<<NN/4, 256, 0, stream>>>(pf2h, el2, er2, offs, srcc, b2, prm, out);
}

// Round 18
// 857.616 us; speedup vs baseline: 1.1588x; 1.1588x over previous
//
#include <hip/hip_runtime.h>

#define NN 100000
#define EE 1700000
#define F1 256
#define NH 8
#define HF 64
#define C1 512
#define C2 40
#define EPS 1e-6f

// ---- ws layout (bytes) ----
#define OF_PF1   ((size_t)0)                       // N*512*2 bf16 (ft1 -> pf1 in place)
#define OF_HCAT  (OF_PF1  + 102400000ULL)          // N*512*2 f16 hcat; pre-agg1 reused as xh/Wh; post-gemm2 reused as pf2h
#define OF_FT2   (OF_HCAT + 102400000ULL)          // N*40*4 f32
#define OF_EL1   (OF_FT2  + 16000000ULL)           // N*8*4
#define OF_ER1   (OF_EL1  + 3200000ULL)
#define OF_EL2   (OF_ER1  + 3200000ULL)            // N*4
#define OF_ER2   (OF_EL2  + 400000ULL)
#define OF_DEG   (OF_ER2  + 400000ULL)             // N*4
#define OF_OFFS  (OF_DEG  + 400000ULL)             // (N+1)*4 padded
#define OF_CUR   (OF_OFFS + 400128ULL)             // N*4
#define OF_SRCC  (OF_CUR  + 400000ULL)             // E*4
#define OF_BSUM  (OF_SRCC + 6800000ULL)            // 2048
#define OF_BOFF  (OF_BSUM + 2048ULL)               // 2048
#define OF_PRM   (OF_BOFF + 2048ULL)               // params block (1KB)
#define OF_W2H   (OF_PRM  + 1024ULL)               // 48*512*2 = 49KB f16
// overlays inside HCAT region:
#define OF_XH    (OF_HCAT)                         // x f16, 51.2MB (dead after gemm1)
#define OF_WH    (OF_HCAT + 51200000ULL)           // W1 f16, 256KB (dead after gemm1)
#define OF_PF2H  (OF_HCAT)                         // pf2 f16, 8MB (written after gemm2; hcat dead)

// params block: [0..7] minkey1(u32), [8] minkey2(u32), [16..23] pe1, [24..31] ipe1, [32] pe2, [33] ipe2

typedef _Float16 f16x8 __attribute__((ext_vector_type(8)));
typedef _Float16 f16x4 __attribute__((ext_vector_type(4)));
typedef float f32x4 __attribute__((ext_vector_type(4)));

__device__ __forceinline__ unsigned f2key(float f){
  unsigned u = __float_as_uint(f);
  return (u & 0x80000000u) ? ~u : (u | 0x80000000u);
}
__device__ __forceinline__ float key2f(unsigned k){
  unsigned u = (k & 0x80000000u) ? (k & 0x7FFFFFFFu) : ~k;
  return __uint_as_float(u);
}
__device__ __forceinline__ unsigned short f2b(float f){  // f32 -> bf16 RNE
  unsigned u = __float_as_uint(f);
  unsigned r = u + 0x7FFFu + ((u >> 16) & 1u);
  return (unsigned short)(r >> 16);
}
__device__ __forceinline__ float b2f(unsigned short b){
  return __uint_as_float(((unsigned)b) << 16);
}
__device__ __forceinline__ float leaky(float e){ return e >= 0.f ? e : 0.2f*e; }

__device__ __forceinline__ void gload16(const _Float16* g, char* l){
  __builtin_amdgcn_global_load_lds((const __attribute__((address_space(1))) void*)g,
                                   (__attribute__((address_space(3))) void*)l, 16, 0, 0);
}

// ---------------- init ----------------
__global__ void k_init(const float* __restrict__ p1, const float* __restrict__ p2, unsigned* __restrict__ prm){
  int t = threadIdx.x;
  float* prf = (float*)prm;
  if (t < 8){
    prm[t] = 0xFFFFFFFFu;
    float pe = 1.f/(1.f + __expf(-p1[t])) + 1.0f;
    prf[16 + t] = pe;
    prf[24 + t] = 1.f/pe;
  }
  if (t == 0){
    prm[8] = 0xFFFFFFFFu;
    float pe = 1.f/(1.f + __expf(-p2[0])) + 1.0f;
    prf[32] = pe;
    prf[33] = 1.f/pe;
  }
}

__global__ void k_zero_deg(int* __restrict__ deg){
  int i = blockIdx.x*256 + threadIdx.x;
  if (i < NN) deg[i] = 0;
}

// ---------------- f32 -> f16 convert (8 elems/thread); used for x and W1 ----------------
__global__ void k_cvt16(const float* __restrict__ in, _Float16* __restrict__ out){
  int i = blockIdx.x*256 + threadIdx.x;
  const float4* p = (const float4*)in + (size_t)i*2;
  float4 a = p[0], b = p[1];
  f16x8 h = {(_Float16)a.x,(_Float16)a.y,(_Float16)a.z,(_Float16)a.w,
             (_Float16)b.x,(_Float16)b.y,(_Float16)b.z,(_Float16)b.w};
  *((f16x8*)out + i) = h;
}

// W2 [40][512] f32 -> W2h [48][512] f16, rows 40..47 zero
__global__ void k_cvtW2(const float* __restrict__ W2, _Float16* __restrict__ W2h){
  int i = blockIdx.x*256 + threadIdx.x;   // 96 blocks: 24576 elems
  int row = i >> 9, col = i & 511;
  W2h[i] = (row < C2) ? (_Float16)W2[row*C1 + col] : (_Float16)0.f;
}

// ---------------- GEMM1 (MFMA fp16, r13 structure: 4 K-steps, BM=128) + fused el1/er1 + per-head min ----------------
// r15/r16/r17 restructures (BM=64, single-barrier variants) all regressed vs this (183us measured r14).
// Structural floor for this decomposition: K=256 with 200MB output stream -> staging-dominated.
#define G1_BM 128
#define G1_BN 128
#define G1_BK 64
__global__ __launch_bounds__(256) void k_gemm1(const _Float16* __restrict__ xh, const _Float16* __restrict__ Wh,
                                               const float* __restrict__ al1, const float* __restrict__ ar1,
                                               unsigned short* __restrict__ ft1b,
                                               float* __restrict__ el1, float* __restrict__ er1,
                                               unsigned* __restrict__ prm){
  __shared__ __align__(16) char smem[35840];
  char* Abase = smem;            // 16KB
  char* Bbase = smem + 16384;    // 16KB
  unsigned short (*Cs)[136] = (unsigned short (*)[136])smem;  // 34816B, overlays A/B after K-loop

  int t = threadIdx.x;
  int lane = t & 63, w = t >> 6;
  int wr = w >> 1, wc = w & 1;
  int ct = blockIdx.x * G1_BN;
  int rt = blockIdx.y * G1_BM;

  int lr8 = lane >> 3;              // dest row within 8-row chunk (== row&7)
  int gcs = (lane & 7) ^ lr8;       // swizzled source granule col

  f32x4 zero = {0.f,0.f,0.f,0.f};
  f32x4 acc[4][4];
  #pragma unroll
  for (int m=0;m<4;m++)
    #pragma unroll
    for (int n=0;n<4;n++) acc[m][n] = zero;

  for (int kt = 0; kt < F1; kt += G1_BK){
    #pragma unroll
    for (int i = 0; i < 4; i++){
      int ch = w*4 + i;                 // chunk 0..15, 1KB each
      int row = ch*8 + lr8;             // dest tile row 0..127
      int ga = min(rt + row, NN-1);     // clamp OOB rows (results discarded)
      gload16(xh + (size_t)ga*F1 + kt + gcs*8, Abase + ch*1024);
      gload16(Wh + (size_t)(ct+row)*F1 + kt + gcs*8, Bbase + ch*1024);
    }
    __syncthreads();
    #pragma unroll
    for (int kk = 0; kk < 2; kk++){
      f16x8 af[4], bf[4];
      #pragma unroll
      for (int m=0;m<4;m++){
        int row = wr*64 + m*16 + (lane & 15);
        int g = kk*4 + (lane >> 4);
        af[m] = *(f16x8*)(Abase + ((row*8 + (g ^ (row & 7)))<<4));
      }
      #pragma unroll
      for (int n=0;n<4;n++){
        int row = wc*64 + n*16 + (lane & 15);
        int g = kk*4 + (lane >> 4);
        bf[n] = *(f16x8*)(Bbase + ((row*8 + (g ^ (row & 7)))<<4));
      }
      #pragma unroll
      for (int m=0;m<4;m++)
        #pragma unroll
        for (int n=0;n<4;n++)
          acc[m][n] = __builtin_amdgcn_mfma_f32_16x16x32_f16(af[m], bf[n], acc[m][n], 0, 0, 0);
    }
    __syncthreads();
  }

  // epilogue: bf16 tile -> LDS; per-head min; fused el1/er1 (each wave owns (row-block, head) fully)
  int h = (ct >> 6) + wc;
  int c0 = lane & 15;
  float alc[4], arc[4];
  #pragma unroll
  for (int n=0;n<4;n++){
    alc[n] = al1[h*HF + n*16 + c0];
    arc[n] = ar1[h*HF + n*16 + c0];
  }
  unsigned kmin = 0xFFFFFFFFu;
  #pragma unroll
  for (int m=0;m<4;m++){
    float elp[4] = {0.f,0.f,0.f,0.f};
    float erp[4] = {0.f,0.f,0.f,0.f};
    #pragma unroll
    for (int n=0;n<4;n++){
      int cl = wc*64 + n*16 + c0;
      int rl = wr*64 + m*16 + (lane >> 4)*4;
      #pragma unroll
      for (int j=0;j<4;j++){
        unsigned short ub = f2b(acc[m][n][j]);
        float vr = b2f(ub);
        Cs[rl + j][cl] = ub;
        kmin = min(kmin, f2key(vr));
        elp[j] += vr*alc[n];
        erp[j] += vr*arc[n];
      }
    }
    #pragma unroll
    for (int j=0;j<4;j++){
      #pragma unroll
      for (int off=1; off<16; off<<=1){
        elp[j] += __shfl_xor(elp[j], off);
        erp[j] += __shfl_xor(erp[j], off);
      }
      int row = rt + wr*64 + m*16 + (lane >> 4)*4 + j;
      if (c0 == 0 && row < NN){
        el1[(size_t)row*8 + h] = elp[j];
        er1[(size_t)row*8 + h] = erp[j];
      }
    }
  }
  #pragma unroll
  for (int off=1; off<64; off<<=1) kmin = min(kmin, (unsigned)__shfl_xor((int)kmin, off));
  if (lane == 0) atomicMin(&prm[h], kmin);
  __syncthreads();

  #pragma unroll
  for (int p = 0; p < 8; p++){
    int flat = p*256 + t;
    int row = flat >> 4;
    int q   = flat & 15;
    int gr = rt + row;
    if (gr < NN){
      uint4 v = *(const uint4*)&Cs[row][q*8];
      *(uint4*)&ft1b[(size_t)gr*C1 + ct + q*8] = v;
    }
  }
}

// ---------------- CSR build ----------------
__global__ void k_count(const int* __restrict__ dst, int* __restrict__ deg){
  int e = blockIdx.x*256 + threadIdx.x;
  if (e < EE) atomicAdd(&deg[dst[e]], 1);
}
__global__ void k_scan1(const int* __restrict__ deg, int* __restrict__ offs, int* __restrict__ bsum){
  __shared__ int s[256];
  int t = threadIdx.x; int i = blockIdx.x*256 + t;
  int v = (i < NN) ? deg[i] : 0;
  s[t] = v; __syncthreads();
  for (int off=1; off<256; off<<=1){
    int tmp = (t>=off) ? s[t-off] : 0;
    __syncthreads(); s[t] += tmp; __syncthreads();
  }
  if (i < NN) offs[i] = s[t] - v;
  if (t == 255) bsum[blockIdx.x] = s[255];
}
__global__ void k_scan2(int* __restrict__ bsum, int* __restrict__ boff, int nb){
  __shared__ int s[512];
  int t = threadIdx.x;
  int v = (t < nb) ? bsum[t] : 0;
  s[t] = v; __syncthreads();
  for (int off=1; off<512; off<<=1){
    int tmp = (t>=off) ? s[t-off] : 0;
    __syncthreads(); s[t] += tmp; __syncthreads();
  }
  if (t < nb) boff[t] = s[t] - v;
}
__global__ void k_scan3(int* __restrict__ offs, int* __restrict__ cur, const int* __restrict__ boff){
  int i = blockIdx.x*256 + threadIdx.x;
  if (i < NN){
    int v = offs[i] + boff[blockIdx.x];
    offs[i] = v; cur[i] = v;
  }
  if (i == 0) offs[NN] = EE;
}
__global__ void k_fill(const int* __restrict__ src, const int* __restrict__ dst,
                       int* __restrict__ cur, int* __restrict__ srcc){
  int e = blockIdx.x*256 + threadIdx.x;
  if (e < EE){
    int d = dst[e];
    int pos = atomicAdd(&cur[d], 1);
    srcc[pos] = src[e];
  }
}

// ---------------- pf1: elementwise pow in place (bf16, 8/thread) ----------------
__global__ void k_pf1(unsigned short* __restrict__ ft1b, const unsigned* __restrict__ prm){
  int i = blockIdx.x*256 + threadIdx.x;
  const float* prf = (const float*)prm;
  int h = (i >> 3) & 7;
  float mu = key2f(prm[h]);
  float pe = prf[16 + h];
  uint4 q = ((const uint4*)ft1b)[i];
  unsigned r0, r1, r2, r3;
  float v0, v1;
  v0 = b2f((unsigned short)(q.x & 0xFFFFu)) - mu + EPS;
  v1 = b2f((unsigned short)(q.x >> 16)) - mu + EPS;
  r0 = (unsigned)f2b(__expf(pe*__logf(v0))) | ((unsigned)f2b(__expf(pe*__logf(v1))) << 16);
  v0 = b2f((unsigned short)(q.y & 0xFFFFu)) - mu + EPS;
  v1 = b2f((unsigned short)(q.y >> 16)) - mu + EPS;
  r1 = (unsigned)f2b(__expf(pe*__logf(v0))) | ((unsigned)f2b(__expf(pe*__logf(v1))) << 16);
  v0 = b2f((unsigned short)(q.z & 0xFFFFu)) - mu + EPS;
  v1 = b2f((unsigned short)(q.z >> 16)) - mu + EPS;
  r2 = (unsigned)f2b(__expf(pe*__logf(v0))) | ((unsigned)f2b(__expf(pe*__logf(v1))) << 16);
  v0 = b2f((unsigned short)(q.w & 0xFFFFu)) - mu + EPS;
  v1 = b2f((unsigned short)(q.w >> 16)) - mu + EPS;
  r3 = (unsigned)f2b(__expf(pe*__logf(v0))) | ((unsigned)f2b(__expf(pe*__logf(v1))) << 16);
  ((uint4*)ft1b)[i] = make_uint4(r0, r1, r2, r3);
}

// ---------------- layer-1 fused attention + aggregation + elu (2 edge slots in pass 3) ----------------
__global__ __launch_bounds__(256) void k_agg1(const unsigned short* __restrict__ pf1b,
    const float* __restrict__ el1, const float* __restrict__ er1,
    const int* __restrict__ offs, const int* __restrict__ srcc,
    const float* __restrict__ b1, const unsigned* __restrict__ prm,
    _Float16* __restrict__ hcath){
  int lane = threadIdx.x & 63; int w = threadIdx.x >> 6;
  int v = blockIdx.x*4 + w;
  if (v >= NN) return;
  const float* prf = (const float*)prm;
  int h = lane >> 3;
  int s = lane & 7;
  int start = offs[v], end = offs[v+1];
  float erh = er1[(size_t)v*8 + h];

  float m = -INFINITY;
  for (int pos = start + s; pos < end; pos += 8){
    int u = srcc[pos];
    float e = leaky(el1[(size_t)u*8 + h] + erh);
    m = fmaxf(m, e);
  }
  m = fmaxf(m, __shfl_xor(m,1)); m = fmaxf(m, __shfl_xor(m,2)); m = fmaxf(m, __shfl_xor(m,4));
  float S = 0.f;
  for (int pos = start + s; pos < end; pos += 8){
    int u = srcc[pos];
    float e = leaky(el1[(size_t)u*8 + h] + erh);
    S += __expf(e - m);
  }
  S += __shfl_xor(S,1); S += __shfl_xor(S,2); S += __shfl_xor(S,4);
  float invS = 1.f / S;

  int es = lane >> 5;
  int hc = (lane >> 2) & 7;
  int q4 = lane & 3;
  float mh    = __shfl(m,    hc*8);
  float invSh = __shfl(invS, hc*8);
  float erhc  = __shfl(erh,  hc*8);

  float acc[16];
  #pragma unroll
  for (int j=0;j<16;j++) acc[j]=0.f;
  for (int pos = start + es; pos < end; pos += 2){
    int u = srcc[pos];
    float e = leaky(el1[(size_t)u*8 + hc] + erhc);
    float a = __expf(e - mh) * invSh;
    const unsigned short* pr = &pf1b[(size_t)u*C1 + hc*HF + q4*16];
    uint4 qa = *(const uint4*)pr;
    uint4 qb = *(const uint4*)(pr + 8);
    acc[0]  += a*b2f((unsigned short)(qa.x & 0xFFFFu));
    acc[1]  += a*b2f((unsigned short)(qa.x >> 16));
    acc[2]  += a*b2f((unsigned short)(qa.y & 0xFFFFu));
    acc[3]  += a*b2f((unsigned short)(qa.y >> 16));
    acc[4]  += a*b2f((unsigned short)(qa.z & 0xFFFFu));
    acc[5]  += a*b2f((unsigned short)(qa.z >> 16));
    acc[6]  += a*b2f((unsigned short)(qa.w & 0xFFFFu));
    acc[7]  += a*b2f((unsigned short)(qa.w >> 16));
    acc[8]  += a*b2f((unsigned short)(qb.x & 0xFFFFu));
    acc[9]  += a*b2f((unsigned short)(qb.x >> 16));
    acc[10] += a*b2f((unsigned short)(qb.y & 0xFFFFu));
    acc[11] += a*b2f((unsigned short)(qb.y >> 16));
    acc[12] += a*b2f((unsigned short)(qb.z & 0xFFFFu));
    acc[13] += a*b2f((unsigned short)(qb.z >> 16));
    acc[14] += a*b2f((unsigned short)(qb.w & 0xFFFFu));
    acc[15] += a*b2f((unsigned short)(qb.w >> 16));
  }
  #pragma unroll
  for (int j=0;j<16;j++) acc[j] += __shfl_xor(acc[j], 32);

  float mu = key2f(prm[hc]);
  float ipe = prf[24+hc];
  int fb = q4*16 + es*8;
  f16x8 o;
  #pragma unroll
  for (int j=0;j<8;j++){
    float r = __expf(ipe * __logf(acc[es*8 + j] + EPS)) + mu + b1[hc*HF + fb + j];
    o[j] = (_Float16)((r > 0.f) ? r : (__expf(r) - 1.f));
  }
  *(f16x8*)&hcath[(size_t)v*C1 + hc*HF + fb] = o;
}

// ---------------- GEMM2 (MFMA fp16, 44KB LDS, fused el2/er2/min epilogue) ----------------
__global__ __launch_bounds__(256) void k_gemm2(const _Float16* __restrict__ hcath, const _Float16* __restrict__ W2h,
    float* __restrict__ ft2, float* __restrict__ el2, float* __restrict__ er2,
    const float* __restrict__ al2, const float* __restrict__ ar2, unsigned* __restrict__ prm){
  __shared__ __align__(16) char smem[45056];
  char* Abase = smem;            // 32KB: [128 rows][16 granules]
  char* Bbase = smem + 32768;    // 12KB: [48 rows][16 granules]
  __shared__ unsigned mk;
  int t = threadIdx.x;
  int lane = t & 63, w = t >> 6;
  int rt = blockIdx.x * 128;
  if (t == 0) mk = 0xFFFFFFFFu;

  f32x4 zero = {0.f,0.f,0.f,0.f};
  f32x4 acc[2][3];
  #pragma unroll
  for (int m=0;m<2;m++)
    #pragma unroll
    for (int n=0;n<3;n++) acc[m][n] = zero;

  for (int step = 0; step < 4; step++){
    #pragma unroll
    for (int p = 0; p < 8; p++){
      int idx = p*256 + t;
      int row = idx >> 4, g = idx & 15;
      int ga = min(rt + row, NN-1);
      gload16(hcath + (size_t)ga*C1 + step*128 + ((g ^ (row & 7))<<3), Abase + idx*16);
    }
    #pragma unroll
    for (int p = 0; p < 3; p++){
      int idx = p*256 + t;
      int row = idx >> 4, g = idx & 15;
      gload16(W2h + (size_t)row*C1 + step*128 + ((g ^ (row & 7))<<3), Bbase + idx*16);
    }
    __syncthreads();
    #pragma unroll
    for (int kk = 0; kk < 4; kk++){
      f16x8 af[2], bf[3];
      #pragma unroll
      for (int m=0;m<2;m++){
        int row = w*32 + m*16 + (lane & 15);
        int g = kk*4 + (lane >> 4);
        af[m] = *(f16x8*)(Abase + ((row*16 + (g ^ (row & 7)))<<4));
      }
      #pragma unroll
      for (int n=0;n<3;n++){
        int row = n*16 + (lane & 15);
        int g = kk*4 + (lane >> 4);
        bf[n] = *(f16x8*)(Bbase + ((row*16 + (g ^ (row & 7)))<<4));
      }
      #pragma unroll
      for (int m=0;m<2;m++)
        #pragma unroll
        for (int n=0;n<3;n++)
          acc[m][n] = __builtin_amdgcn_mfma_f32_16x16x32_f16(af[m], bf[n], acc[m][n], 0, 0, 0);
    }
    __syncthreads();
  }

  int c0 = lane & 15;
  unsigned kmin = 0xFFFFFFFFu;
  #pragma unroll
  for (int m=0;m<2;m++){
    float elp[4] = {0.f,0.f,0.f,0.f};
    float erp[4] = {0.f,0.f,0.f,0.f};
    #pragma unroll
    for (int n=0;n<3;n++){
      int col = n*16 + c0;
      bool okc = (col < C2);
      float alc = okc ? al2[col] : 0.f;
      float arc = okc ? ar2[col] : 0.f;
      int rbase = rt + w*32 + m*16 + (lane >> 4)*4;
      #pragma unroll
      for (int j=0;j<4;j++){
        float vv = acc[m][n][j];
        int row = rbase + j;
        if (okc && row < NN){
          ft2[(size_t)row*C2 + col] = vv;
          elp[j] += vv*alc; erp[j] += vv*arc;
          kmin = min(kmin, f2key(vv));
        }
      }
    }
    #pragma unroll
    for (int j=0;j<4;j++){
      #pragma unroll
      for (int off=1; off<16; off<<=1){
        elp[j] += __shfl_xor(elp[j], off);
        erp[j] += __shfl_xor(erp[j], off);
      }
      int row = rt + w*32 + m*16 + (lane >> 4)*4 + j;
      if (c0 == 0 && row < NN){ el2[row] = elp[j]; er2[row] = erp[j]; }
    }
  }
  #pragma unroll
  for (int off=1; off<64; off<<=1) kmin = min(kmin, (unsigned)__shfl_xor((int)kmin, off));
  if (lane == 0) atomicMin(&mk, kmin);
  __syncthreads();
  if (t == 0) atomicMin(&prm[8], mk);
}

// ---------------- transform2: pf2h (f16) = pow(ft2 - mu + eps, pe) ----------------
__global__ void k_transform2(const float* __restrict__ ft2, _Float16* __restrict__ pf2h,
                             const unsigned* __restrict__ prm){
  int i = blockIdx.x*256 + threadIdx.x;
  if (i >= NN*C2) return;
  const float* prf = (const float*)prm;
  float mu = key2f(prm[8]);
  float pe = prf[32];
  float v = ft2[i];
  pf2h[i] = (_Float16)__expf(pe * __logf(v - mu + EPS));
}

// ---------------- layer-2 fused attention + aggregation + log_softmax (online softmax + edge-parallel) ----------------
__global__ __launch_bounds__(256) void k_agg2(const _Float16* __restrict__ pf2h,
    const float* __restrict__ el2, const float* __restrict__ er2,
    const int* __restrict__ offs, const int* __restrict__ srcc,
    const float* __restrict__ b2, const unsigned* __restrict__ prm,
    float* __restrict__ out){
  int lane = threadIdx.x & 63; int w = threadIdx.x >> 6;
  int v = blockIdx.x*4 + w;
  if (v >= NN) return;
  const float* prf = (const float*)prm;
  int start = offs[v], end = offs[v+1];
  float erv = er2[v];

  float m = -INFINITY, S = 0.f;
  for (int pos = start + lane; pos < end; pos += 64){
    float e = leaky(el2[srcc[pos]] + erv);
    float d = e - m;
    if (d > 0.f){ S = S*__expf(-d) + 1.f; m = e; }
    else S += __expf(d);
  }
  float mAll = m;
  #pragma unroll
  for (int off=1; off<64; off<<=1) mAll = fmaxf(mAll, __shfl_xor(mAll, off));
  S *= __expf(m - mAll);
  #pragma unroll
  for (int off=1; off<64; off<<=1) S += __shfl_xor(S, off);
  float invS = 1.f / S;
  m = mAll;

  int s = lane >> 4;
  int c = lane & 15;
  float a0=0.f, a1=0.f, a2=0.f, a3=0.f;
  for (int pos = start + s; pos < end; pos += 4){
    int u = srcc[pos];
    float a = __expf(leaky(el2[u] + erv) - m) * invS;
    if (c < 10){
      f16x4 q = *(const f16x4*)&pf2h[(size_t)u*C2 + c*4];
      a0 += a*(float)q[0]; a1 += a*(float)q[1]; a2 += a*(float)q[2]; a3 += a*(float)q[3];
    }
  }
  a0 += __shfl_xor(a0,16); a1 += __shfl_xor(a1,16); a2 += __shfl_xor(a2,16); a3 += __shfl_xor(a3,16);
  a0 += __shfl_xor(a0,32); a1 += __shfl_xor(a1,32); a2 += __shfl_xor(a2,32); a3 += __shfl_xor(a3,32);

  float y[4];
  float mx;
  if (c < 10){
    float mu = key2f(prm[8]);
    float ipe = prf[33];
    float av[4] = {a0,a1,a2,a3};
    #pragma unroll
    for (int j=0;j<4;j++) y[j] = __expf(ipe * __logf(av[j] + EPS)) + mu + b2[c*4 + j];
    mx = fmaxf(fmaxf(y[0],y[1]), fmaxf(y[2],y[3]));
  } else {
    y[0]=y[1]=y[2]=y[3]=-INFINITY;
    mx = -INFINITY;
  }
  mx = fmaxf(mx, __shfl_xor(mx,1)); mx = fmaxf(mx, __shfl_xor(mx,2));
  mx = fmaxf(mx, __shfl_xor(mx,4)); mx = fmaxf(mx, __shfl_xor(mx,8));
  float se = 0.f;
  if (c < 10){
    #pragma unroll
    for (int j=0;j<4;j++) se += __expf(y[j] - mx);
  }
  se += __shfl_xor(se,1); se += __shfl_xor(se,2); se += __shfl_xor(se,4); se += __shfl_xor(se,8);
  float ls = __logf(se);
  if (s == 0 && c < 10){
    float4 o = make_float4(y[0]-mx-ls, y[1]-mx-ls, y[2]-mx-ls, y[3]-mx-ls);
    *(float4*)&out[(size_t)v*C2 + c*4] = o;
  }
}

// ---------------- host ----------------
extern "C" void kernel_launch(void* const* d_in, const int* in_sizes, int n_in,
                              void* d_out, int out_size, void* d_ws, size_t ws_size,
                              hipStream_t stream){
  const float* x   = (const float*)d_in[0];
  const int*   src = (const int*)d_in[1];
  const int*   dst = (const int*)d_in[2];
  const float* W1  = (const float*)d_in[3];
  const float* al1 = (const float*)d_in[4];
  const float* ar1 = (const float*)d_in[5];
  const float* b1  = (const float*)d_in[6];
  const float* p1  = (const float*)d_in[7];
  const float* W2  = (const float*)d_in[8];
  const float* al2 = (const float*)d_in[9];
  const float* ar2 = (const float*)d_in[10];
  const float* b2  = (const float*)d_in[11];
  const float* p2  = (const float*)d_in[12];
  float* out = (float*)d_out;
  char* ws = (char*)d_ws;

  unsigned short* pf1b  = (unsigned short*)(ws + OF_PF1);
  _Float16* hcath = (_Float16*)(ws + OF_HCAT);
  _Float16* xh  = (_Float16*)(ws + OF_XH);
  _Float16* Wh  = (_Float16*)(ws + OF_WH);
  _Float16* W2h = (_Float16*)(ws + OF_W2H);
  _Float16* pf2h = (_Float16*)(ws + OF_PF2H);
  float* ft2   = (float*)(ws + OF_FT2);
  float* el1   = (float*)(ws + OF_EL1);
  float* er1   = (float*)(ws + OF_ER1);
  float* el2   = (float*)(ws + OF_EL2);
  float* er2   = (float*)(ws + OF_ER2);
  int*   deg   = (int*)(ws + OF_DEG);
  int*   offs  = (int*)(ws + OF_OFFS);
  int*   cur   = (int*)(ws + OF_CUR);
  int*   srcc  = (int*)(ws + OF_SRCC);
  int*   bsum  = (int*)(ws + OF_BSUM);
  int*   boff  = (int*)(ws + OF_BOFF);
  unsigned* prm = (unsigned*)(ws + OF_PRM);

  const int NB1 = (NN + 255)/256;
  const int NBE = (EE + 255)/256;

  k_init<<<1, 64, 0, stream>>>(p1, p2, prm);
  k_zero_deg<<<NB1, 256, 0, stream>>>(deg);
  k_cvt16<<<12500, 256, 0, stream>>>(x, xh);
  k_cvt16<<<64, 256, 0, stream>>>(W1, Wh);
  k_cvtW2<<<96, 256, 0, stream>>>(W2, W2h);
  k_gemm1<<<dim3(C1/G1_BN, (NN + G1_BM - 1)/G1_BM), 256, 0, stream>>>(xh, Wh, al1, ar1, pf1b, el1, er1, prm);
  k_count<<<NBE, 256, 0, stream>>>(dst, deg);
  k_scan1<<<NB1, 256, 0, stream>>>(deg, offs, bsum);
  k_scan2<<<1, 512, 0, stream>>>(bsum, boff, NB1);
  k_scan3<<<NB1, 256, 0, stream>>>(offs, cur, boff);
  k_fill<<<NBE, 256, 0, stream>>>(src, dst, cur, srcc);
  k_pf1<<<25000, 256, 0, stream>>>(pf1b, prm);
  k_agg1<<<NN/4, 256, 0, stream>>>(pf1b, el1, er1, offs, srcc, b1, prm, hcath);
  k_gemm2<<<(NN + 127)/128, 256, 0, stream>>>(hcath, W2h, ft2, el2, er2, al2, ar2, prm);
  k_transform2<<<(NN*C2 + 255)/256, 256, 0, stream>>>(ft2, pf2h, prm);
  k_agg2<<<NN/4, 256, 0, stream>>>(pf2h, el2, er2, offs, srcc, b2, prm, out);
}